// Round 6
// baseline (227.161 us; speedup 1.0000x reference)
//
#include <hip/hip_runtime.h>
#include <cstdint>

// ECT loss via histogram factorization (R2 algebra, R2's LDS-atomic
// serialization fixed by lane=(direction,bc-pair) transposition).
//
// A[r,d,bc] = sum_p dw[p,bc] * sigmoid(8*(lin_r - nh_{p,d}))
//           ~= sum_b H[d][b][bc] * sigmoid(8*(lin_r - t_b))     (lerp binning)
// c2 = -(c0+c1); loss = mean over 12288.
//
// ws layout (floats): [0, nrep*32768) replica hists; [nrep*32768, +32768) Hsum.
// hist/Hsum index: bin*128 + bc*32 + d  (bank = d -> conflict-free atomics);
// Hsum is transposed by ect_reduce to bin*128 + d*4 + bc for float4 conv loads.

#define P_TOT 110592
#define BVOX 432            // voxels per bin-block (110592 / 256)
#define B_BINS 256
#define HWORDS (B_BINS * 128)   // 32768 floats = 128 KB

#define RADIUS_EXPR (1.1f * 1.7320508075688772f)  // bit-matches ref (R1-R5)
#define INVHB 66.9200543f    // 255 / (2*RADIUS)
#define HB 0.0149431834f     // 2*RADIUS/255
#define SSTEP 0.0604843139f  // 2*RADIUS/63

__device__ __forceinline__ uint32_t rotl32(uint32_t x, int d) {
  return (x << d) | (x >> (32 - d));
}

// threefry2x32, key = (0,17) — bit-exact vs jax (verified R1-R5)
__device__ __forceinline__ void threefry_0_17(uint32_t x0, uint32_t x1,
                                              uint32_t& o0, uint32_t& o1) {
  const uint32_t ks0 = 0u, ks1 = 17u, ks2 = 0x1BD11BDAu ^ 0u ^ 17u;
  x0 += ks0; x1 += ks1;
#define R4(a,b,c,dd) \
  x0 += x1; x1 = rotl32(x1,(a)); x1 ^= x0; \
  x0 += x1; x1 = rotl32(x1,(b)); x1 ^= x0; \
  x0 += x1; x1 = rotl32(x1,(c)); x1 ^= x0; \
  x0 += x1; x1 = rotl32(x1,(dd)); x1 ^= x0;
  R4(13,15,26,6)   x0 += ks1; x1 += ks2 + 1u;
  R4(17,29,16,24)  x0 += ks2; x1 += ks0 + 2u;
  R4(13,15,26,6)   x0 += ks0; x1 += ks1 + 3u;
  R4(17,29,16,24)  x0 += ks1; x1 += ks2 + 4u;
  R4(13,15,26,6)   x0 += ks2; x1 += ks0 + 5u;
#undef R4
  o0 = x0; o1 = x1;
}

// XLA ErfInv32 — bit-exact vs jax (verified R1-R5)
__device__ __forceinline__ float erfinv_f32(float x) {
  float w = -log1pf(-x * x);
  float p;
  if (w < 5.0f) {
    w = w - 2.5f;
    p = 2.81022636e-08f;
    p = fmaf(p, w, 3.43273939e-07f);
    p = fmaf(p, w, -3.5233877e-06f);
    p = fmaf(p, w, -4.39150654e-06f);
    p = fmaf(p, w, 0.00021858087f);
    p = fmaf(p, w, -0.00125372503f);
    p = fmaf(p, w, -0.00417768164f);
    p = fmaf(p, w, 0.246640727f);
    p = fmaf(p, w, 1.50140941f);
  } else {
    w = sqrtf(w) - 3.0f;
    p = -0.000200214257f;
    p = fmaf(p, w, 0.000100950558f);
    p = fmaf(p, w, 0.00134934322f);
    p = fmaf(p, w, 0.000337081863f);
    p = fmaf(p, w, 0.00573950773f);
    p = fmaf(p, w, -0.0076224613f);
    p = fmaf(p, w, 0.00943887047f);
    p = fmaf(p, w, 1.00167406f);
    p = fmaf(p, w, 2.83297682f);
  }
  return p * x;
}

// 256 blocks x 1024 threads. Block bins 432 voxels x 32 dirs into LDS hist,
// then atomic-merges into replica (blockIdx % nrep).
__global__ __launch_bounds__(1024) void ect_bin(
    const float* __restrict__ pred, const int* __restrict__ tgt,
    float* __restrict__ grep, int nrep) {
  __shared__ float dirs[96];
  __shared__ float4 voxc[BVOX];
  __shared__ float4 voxdw[BVOX];
  __shared__ float hist[HWORDS];   // 128 KB; index bin*128 + bc*32 + d

  const int t = threadIdx.x;
  const int bx = blockIdx.x;

  if (t < 96) {
    uint32_t o0, o1;
    threefry_0_17(0u, (uint32_t)t, o0, o1);
    uint32_t bits = o0 ^ o1;
    float u = __uint_as_float((bits >> 9) | 0x3F800000u) - 1.0f;
    const float lo = -0.99999994f;
    float v = fmaf(u, 2.0f, lo);
    v = fmaxf(v, lo);
    dirs[t] = 1.41421356237f * erfinv_f32(v);
  }
  __syncthreads();
  if (t < 32) {
    float a = dirs[t], b = dirs[32 + t], c = dirs[64 + t];
    float n = fmaxf(sqrtf(a * a + b * b + c * c), 1e-12f);
    dirs[t] = a / n; dirs[32 + t] = b / n; dirs[64 + t] = c / n;
  }
  // stage coords + dw (softmax - onehot) for the block's 432 voxels
  if (t < BVOX) {
    int p = bx * BVOX + t;
    int ix = p / 2304; int rem = p - ix * 2304;
    int iy = rem / 48; int iz = rem - iy * 48;
    const float delta = 2.0f / 47.0f;
    voxc[t] = float4{(float)ix * delta - 1.0f, (float)iy * delta - 1.0f,
                     (float)iz * delta - 1.0f, 0.0f};
    float w[4];
#pragma unroll
    for (int b = 0; b < 2; b++) {
      const float* pb = pred + b * (3 * P_TOT) + p;
      float x0 = pb[0], x1 = pb[P_TOT], x2 = pb[2 * P_TOT];
      float m = fmaxf(x0, fmaxf(x1, x2));
      float e0 = __expf(x0 - m), e1 = __expf(x1 - m), e2 = __expf(x2 - m);
      float inv = 1.0f / (e0 + e1 + e2);
      int tg = tgt[b * P_TOT + p];
      w[b * 2 + 0] = e0 * inv - ((tg == 0) ? 1.0f : 0.0f);
      w[b * 2 + 1] = e1 * inv - ((tg == 1) ? 1.0f : 0.0f);
    }
    voxdw[t] = float4{w[0], w[1], w[2], w[3]};
  }
  // zero hist (float4 stores)
  {
    float4* h4 = reinterpret_cast<float4*>(hist);
    for (int i = t; i < HWORDS / 4; i += 1024)
      h4[i] = float4{0.f, 0.f, 0.f, 0.f};
  }
  __syncthreads();

  // lane = (d, h): d = direction, h = bc-pair. One voxel per wave-iteration.
  const int d = t & 31;
  const int h = (t >> 5) & 1;
  const int wave = t >> 6;
  const float dx = dirs[d], dy = dirs[32 + d], dz = dirs[64 + d];

  for (int v = wave; v < BVOX; v += 16) {
    float4 c = voxc[v];
    float4 w4 = voxdw[v];
    float wa = h ? w4.z : w4.x;
    float wb = h ? w4.w : w4.y;
    float nh = fmaf(c.z, dz, fmaf(c.y, dy, c.x * dx));
    float binf = fmaf(nh, INVHB, 127.5f);   // (nh + RADIUS)/HB; in [11.6, 243.4]
    float fl = floorf(binf);
    int ib = (int)fl;
    float fr = binf - fl;
    float g0 = 1.0f - fr;
    // hist[ib][2h][d], [ib][2h+1][d], [ib+1][2h][d], [ib+1][2h+1][d]
    float* hp = &hist[ib * 128 + h * 64 + d];   // bank = d for all four
    atomicAdd(hp, wa * g0);
    atomicAdd(hp + 32, wb * g0);
    atomicAdd(hp + 128, wa * fr);
    atomicAdd(hp + 160, wb * fr);
  }
  __syncthreads();

  // merge into global replica
  float* rep = grep + (size_t)(bx % nrep) * HWORDS;
  for (int i = t; i < HWORDS; i += 1024) {
    float v = hist[i];
    if (v != 0.0f) atomicAdd(&rep[i], v);
  }
}

// 32 blocks x 1024: Hsum (transposed to bin*128 + d*4 + bc) = sum of replicas.
__global__ __launch_bounds__(1024) void ect_reduce(
    const float* __restrict__ grep, int nrep, float* __restrict__ Hsum,
    float* __restrict__ out) {
  int i = blockIdx.x * 1024 + threadIdx.x;   // output index
  int b = i >> 7, rem = i & 127;
  int d = rem >> 2, bc = rem & 3;
  int src = b * 128 + bc * 32 + d;
  float s = 0.0f;
  for (int r = 0; r < nrep; r++) s += grep[(size_t)r * HWORDS + src];
  Hsum[i] = s;
  if (i == 0) out[0] = 0.0f;
}

// 64 blocks (one r each) x 256 threads (d = t&31, g = t>>5 over 8 bin-chunks).
__global__ __launch_bounds__(256) void ect_conv(
    const float* __restrict__ Hsum, float* __restrict__ out) {
  __shared__ float accs[32][4];
  const int t = threadIdx.x;
  const int r = blockIdx.x;
  const int d = t & 31;
  const int g = t >> 5;
  if (t < 32) { accs[t][0] = accs[t][1] = accs[t][2] = accs[t][3] = 0.0f; }
  __syncthreads();

  float a0 = 0.f, a1 = 0.f, a2 = 0.f, a3 = 0.f;
#pragma unroll 4
  for (int bb = 0; bb < 32; bb++) {
    int b = g * 32 + bb;
    float x = 8.0f * fmaf((float)r, SSTEP, -(float)b * HB);
    float sg = 1.0f / (1.0f + __expf(-x));
    float4 H4 = *(const float4*)(Hsum + (size_t)b * 128 + d * 4);
    a0 = fmaf(H4.x, sg, a0); a1 = fmaf(H4.y, sg, a1);
    a2 = fmaf(H4.z, sg, a2); a3 = fmaf(H4.w, sg, a3);
  }
  atomicAdd(&accs[d][0], a0);
  atomicAdd(&accs[d][1], a1);
  atomicAdd(&accs[d][2], a2);
  atomicAdd(&accs[d][3], a3);
  __syncthreads();

  if (t < 32) {
    float b0c0 = accs[t][0], b0c1 = accs[t][1];
    float b1c0 = accs[t][2], b1c1 = accs[t][3];
    float s = b0c0 * b0c0 + b0c1 * b0c1 + (b0c0 + b0c1) * (b0c0 + b0c1)
            + b1c0 * b1c0 + b1c1 * b1c1 + (b1c0 + b1c1) * (b1c0 + b1c1);
#pragma unroll
    for (int off = 16; off > 0; off >>= 1) s += __shfl_down(s, off, 32);
    if (t == 0) atomicAdd(out, s * (1.0f / 12288.0f));
  }
}

extern "C" void kernel_launch(void* const* d_in, const int* in_sizes, int n_in,
                              void* d_out, int out_size, void* d_ws, size_t ws_size,
                              hipStream_t stream) {
  const float* pred = (const float*)d_in[0];
  const int* tgt = (const int*)d_in[1];
  float* ws = (float*)d_ws;
  float* out = (float*)d_out;

  // replicas + Hsum must fit: (nrep+1) * 128 KB <= ws_size
  size_t cap = ws_size / (HWORDS * sizeof(float));
  int nrep = (cap > 2) ? (int)((cap - 1 < 16) ? cap - 1 : 16) : 1;
  float* grep = ws;
  float* Hsum = ws + (size_t)nrep * HWORDS;

  hipMemsetAsync(grep, 0, (size_t)nrep * HWORDS * sizeof(float), stream);
  hipLaunchKernelGGL(ect_bin, dim3(256), dim3(1024), 0, stream,
                     pred, tgt, grep, nrep);
  hipLaunchKernelGGL(ect_reduce, dim3(32), dim3(1024), 0, stream,
                     grep, nrep, Hsum, out);
  hipLaunchKernelGGL(ect_conv, dim3(64), dim3(256), 0, stream, Hsum, out);
}